// Round 1
// baseline (537.817 us; speedup 1.0000x reference)
//
#include <hip/hip_runtime.h>
#include <stdint.h>

#define N_TOK 16384
#define DDIM  1024
#define HDIM  4096
#define NEXP  8
#define BM    128
#define MAXMT 136   // N_TOK/BM + NEXP padded tiles upper bound

typedef __attribute__((ext_vector_type(8))) short short8;
typedef __attribute__((ext_vector_type(4))) float f32x4;

__device__ __forceinline__ unsigned short f2b(float f) {
    union { float f; unsigned int u; } x; x.f = f;
    unsigned int r = x.u + 0x7FFFu + ((x.u >> 16) & 1u);
    return (unsigned short)(r >> 16);
}

// K1: router (fp64 accumulate, argmax == reference) + x -> bf16 cast.
// One wave per token; Wr (8x1024 f32 = 32KB) staged in LDS.
__global__ __launch_bounds__(256)
void k_router_cast(const float* __restrict__ x, const float* __restrict__ Wr,
                   const float* __restrict__ br, unsigned short* __restrict__ xb,
                   int* __restrict__ eid, int* __restrict__ counts)
{
    __shared__ float wr[NEXP * DDIM];
    const int t = threadIdx.x;
    for (int i = t; i < NEXP * DDIM / 4; i += 256)
        ((float4*)wr)[i] = ((const float4*)Wr)[i];
    __syncthreads();
    const int lane = t & 63;
    const int n = blockIdx.x * 4 + (t >> 6);
    const float* xr = x + (size_t)n * DDIM;
    double acc[NEXP];
#pragma unroll
    for (int e = 0; e < NEXP; ++e) acc[e] = 0.0;
#pragma unroll
    for (int j = 0; j < 4; ++j) {
        const int d = j * 256 + lane * 4;
        float4 v = *(const float4*)(xr + d);
        unsigned long long pk =
            (unsigned long long)(f2b(v.x) | ((unsigned int)f2b(v.y) << 16)) |
            ((unsigned long long)(f2b(v.z) | ((unsigned int)f2b(v.w) << 16)) << 32);
        *(unsigned long long*)(xb + (size_t)n * DDIM + d) = pk;
#pragma unroll
        for (int e = 0; e < NEXP; ++e) {
            const float* w = wr + e * DDIM + d;
            acc[e] += (double)v.x * (double)w[0];
            acc[e] += (double)v.y * (double)w[1];
            acc[e] += (double)v.z * (double)w[2];
            acc[e] += (double)v.w * (double)w[3];
        }
    }
#pragma unroll
    for (int e = 0; e < NEXP; ++e)
#pragma unroll
        for (int off = 32; off > 0; off >>= 1)
            acc[e] += __shfl_down(acc[e], off);
    if (lane == 0) {
        double best = acc[0] + (double)br[0];
        int bi = 0;
#pragma unroll
        for (int e = 1; e < NEXP; ++e) {
            double v = acc[e] + (double)br[e];
            if (v > best) { best = v; bi = e; }   // strict > == first-max tiebreak
        }
        eid[n] = bi;
        atomicAdd(&counts[bi], 1);
    }
}

// K2: tile table from counts (single thread; E=8, <=136 tiles)
__global__ void k_scan(const int* __restrict__ counts, int* __restrict__ texp,
                       int* __restrict__ pbase, int* __restrict__ cursors)
{
    if (threadIdx.x == 0) {
        int tt = 0;
        for (int e = 0; e < NEXP; ++e) {
            pbase[e] = tt * BM;
            cursors[e] = 0;
            const int nt = (counts[e] + BM - 1) / BM;
            for (int i = 0; i < nt; ++i) texp[tt++] = e;
        }
        for (; tt < MAXMT; ++tt) texp[tt] = -1;
    }
}

// K3: scatter token ids into per-expert padded slots
__global__ __launch_bounds__(256)
void k_scatter(const int* __restrict__ eid, const int* __restrict__ pbase,
               int* __restrict__ cursors, int* __restrict__ perm)
{
    const int n = blockIdx.x * 256 + threadIdx.x;
    const int e = eid[n];
    const int slot = pbase[e] + atomicAdd(&cursors[e], 1);
    perm[slot] = n;
}

// K4a: W_comb[e] = bf16(Ws + We[e]); 8 elems/thread, float4 in, uint4 out
__global__ __launch_bounds__(256)
void k_combine_w(const float* __restrict__ Ws, const float* __restrict__ We,
                 unsigned short* __restrict__ wc)
{
    const size_t i = ((size_t)blockIdx.x * 256 + threadIdx.x) * 8;
    const size_t hd = i & (size_t)(HDIM * DDIM - 1);   // H*D = 2^22
    float4 a0 = *(const float4*)(We + i);
    float4 a1 = *(const float4*)(We + i + 4);
    float4 b0 = *(const float4*)(Ws + hd);
    float4 b1 = *(const float4*)(Ws + hd + 4);
    uint4 o;
    o.x = f2b(a0.x + b0.x) | ((unsigned)f2b(a0.y + b0.y) << 16);
    o.y = f2b(a0.z + b0.z) | ((unsigned)f2b(a0.w + b0.w) << 16);
    o.z = f2b(a1.x + b1.x) | ((unsigned)f2b(a1.y + b1.y) << 16);
    o.w = f2b(a1.z + b1.z) | ((unsigned)f2b(a1.w + b1.w) << 16);
    *(uint4*)(wc + i) = o;
}

// K4b: b_comb[e] = bs + be[e]
__global__ __launch_bounds__(256)
void k_combine_b(const float* __restrict__ bs, const float* __restrict__ be,
                 float* __restrict__ bc)
{
    const int i = blockIdx.x * 256 + threadIdx.x;
    bc[i] = bs[i & (HDIM - 1)] + be[i];
}

// K5: gathered GEMM out[tok,h] = xb[tok,:] @ W_comb[e].T + b_comb[e]
// 128x128 tile, BK=64, 4 waves (2x2), 16x16x32 bf16 MFMA, global_load_lds staging.
__global__ __launch_bounds__(256, 2)
void k_gemm(const unsigned short* __restrict__ X, const unsigned short* __restrict__ W,
            const float* __restrict__ bc, const int* __restrict__ perm,
            const int* __restrict__ texp, float* __restrict__ out)
{
    __shared__ unsigned short lA[BM * 64];   // [128 rows][64 k] bf16
    __shared__ unsigned short lB[BM * 64];   // [128 h][64 k]
    const int tm = blockIdx.y;
    const int e = texp[tm];
    if (e < 0) return;                        // block-uniform: safe
    const int tn = blockIdx.x;
    const int t = threadIdx.x;
    const int lane = t & 63;
    const int wid = t >> 6;
    const int wm = wid >> 1, wn = wid & 1;

    // staging geometry: block round r covers rows [32r,32r+32), lane-linear LDS
    const int rowC = t >> 3;                  // 0..31
    const int colE = (t & 7) << 3;            // k elem 0..56

    int tokA[4];
#pragma unroll
    for (int r = 0; r < 4; ++r) {
        const int tok = perm[tm * BM + r * 32 + rowC];
        tokA[r] = tok < 0 ? 0 : tok;          // dummy rows read token 0, never stored
    }
    const unsigned short* Wb = W + ((size_t)e * HDIM + (size_t)tn * 128) * DDIM;

    f32x4 acc[4][4];
#pragma unroll
    for (int m = 0; m < 4; ++m)
#pragma unroll
        for (int n = 0; n < 4; ++n) acc[m][n] = (f32x4){0.f, 0.f, 0.f, 0.f};

    unsigned short* ldsA = &lA[t * 8];        // lane-linear: byte t*16 within round chunk
    unsigned short* ldsB = &lB[t * 8];

    for (int kt = 0; kt < DDIM / 64; ++kt) {
        const int kb = kt * 64;
        __syncthreads();                      // prev compute done before overwrite
#pragma unroll
        for (int r = 0; r < 4; ++r) {
            const unsigned short* src = X + (size_t)tokA[r] * DDIM + kb + colE;
            __builtin_amdgcn_global_load_lds(
                (const __attribute__((address_space(1))) void*)src,
                (__attribute__((address_space(3))) void*)(ldsA + r * 2048), 16, 0, 0);
        }
#pragma unroll
        for (int r = 0; r < 4; ++r) {
            const unsigned short* src = Wb + (size_t)(r * 32 + rowC) * DDIM + kb + colE;
            __builtin_amdgcn_global_load_lds(
                (const __attribute__((address_space(1))) void*)src,
                (__attribute__((address_space(3))) void*)(ldsB + r * 2048), 16, 0, 0);
        }
        __syncthreads();                      // compiler drains vmcnt before s_barrier
#pragma unroll
        for (int ks = 0; ks < 2; ++ks) {
            const int ko = ks * 32 + (lane >> 4) * 8;
            short8 fa[4], fb[4];
#pragma unroll
            for (int m = 0; m < 4; ++m)
                fa[m] = *(const short8*)&lA[(wm * 64 + m * 16 + (lane & 15)) * 64 + ko];
#pragma unroll
            for (int n = 0; n < 4; ++n)
                fb[n] = *(const short8*)&lB[(wn * 64 + n * 16 + (lane & 15)) * 64 + ko];
#pragma unroll
            for (int m = 0; m < 4; ++m)
#pragma unroll
                for (int n = 0; n < 4; ++n)
                    acc[m][n] = __builtin_amdgcn_mfma_f32_16x16x32_bf16(
                        fa[m], fb[n], acc[m][n], 0, 0, 0);
        }
    }

    // epilogue: C/D layout col=lane&15, row=(lane>>4)*4+reg; fused bias, scatter by token
    const int colBase = tn * 128 + wn * 64 + (lane & 15);
    float bias[4];
#pragma unroll
    for (int n = 0; n < 4; ++n) bias[n] = bc[e * HDIM + colBase + n * 16];
    const int rsub = (lane >> 4) * 4;
#pragma unroll
    for (int m = 0; m < 4; ++m) {
        const int rbase = tm * BM + wm * 64 + m * 16 + rsub;
        int tk[4];
#pragma unroll
        for (int j = 0; j < 4; ++j) tk[j] = perm[rbase + j];
#pragma unroll
        for (int n = 0; n < 4; ++n) {
            const int col = colBase + n * 16;
#pragma unroll
            for (int j = 0; j < 4; ++j)
                if (tk[j] >= 0) out[(size_t)tk[j] * HDIM + col] = acc[m][n][j] + bias[n];
        }
    }
}

extern "C" void kernel_launch(void* const* d_in, const int* in_sizes, int n_in,
                              void* d_out, int out_size, void* d_ws, size_t ws_size,
                              hipStream_t stream)
{
    const float* x  = (const float*)d_in[0];
    const float* Ws = (const float*)d_in[1];
    const float* bs = (const float*)d_in[2];
    const float* We = (const float*)d_in[3];
    const float* be = (const float*)d_in[4];
    const float* Wr = (const float*)d_in[5];
    const float* br = (const float*)d_in[6];
    float* out = (float*)d_out;
    char* ws = (char*)d_ws;

    // workspace layout (~100.9 MB)
    unsigned short* xb  = (unsigned short*)(ws + 0);          // 33,554,432 B
    unsigned short* wc  = (unsigned short*)(ws + 33554432);   // 67,108,864 B
    float*          bc  = (float*)(ws + 100663296);           //    131,072 B
    int*            eid = (int*)(ws + 100794368);             //     65,536 B
    int*            perm= (int*)(ws + 100859904);             //     69,632 B
    int*            cnt = (int*)(ws + 100929536);             // 32 B
    int*            cur = (int*)(ws + 100929568);             // 32 B
    int*            pb  = (int*)(ws + 100929600);             // 32 B
    int*            texp= (int*)(ws + 100929632);             // 544 B

    hipMemsetAsync(perm, 0xFF, MAXMT * BM * sizeof(int), stream);
    hipMemsetAsync(cnt, 0, NEXP * sizeof(int), stream);

    k_router_cast<<<N_TOK / 4, 256, 0, stream>>>(x, Wr, br, xb, eid, cnt);
    k_combine_w<<<(NEXP * (size_t)HDIM * DDIM / 8) / 256, 256, 0, stream>>>(Ws, We, wc);
    k_combine_b<<<NEXP * HDIM / 256, 256, 0, stream>>>(bs, be, bc);
    k_scan<<<1, 64, 0, stream>>>(cnt, texp, pb, cur);
    k_scatter<<<N_TOK / 256, 256, 0, stream>>>(eid, pb, cur, perm);
    k_gemm<<<dim3(HDIM / 128, MAXMT), 256, 0, stream>>>(xb, wc, bc, perm, texp, out);
}

// Round 2
// 298.034 us; speedup vs baseline: 1.8045x; 1.8045x over previous
//
#include <hip/hip_runtime.h>
#include <stdint.h>

#define N_TOK 16384
#define DDIM  1024
#define HDIM  4096
#define NEXP  8
#define BM    128
#define MAXMT 136   // N_TOK/BM + NEXP padded tiles upper bound

typedef __attribute__((ext_vector_type(8))) short short8;
typedef __attribute__((ext_vector_type(4))) float f32x4;

__device__ __forceinline__ unsigned short f2b(float f) {
    union { float f; unsigned int u; } x; x.f = f;
    unsigned int r = x.u + 0x7FFFu + ((x.u >> 16) & 1u);
    return (unsigned short)(r >> 16);
}

// K1: router (fp64 accumulate, argmax == reference) + x -> bf16 cast.
// One wave per token; Wr (8x1024 f32 = 32KB) staged in LDS. No global atomics.
__global__ __launch_bounds__(256)
void k_router_cast(const float* __restrict__ x, const float* __restrict__ Wr,
                   const float* __restrict__ br, unsigned short* __restrict__ xb,
                   int* __restrict__ eid)
{
    __shared__ float wr[NEXP * DDIM];
    const int t = threadIdx.x;
    for (int i = t; i < NEXP * DDIM / 4; i += 256)
        ((float4*)wr)[i] = ((const float4*)Wr)[i];
    __syncthreads();
    const int lane = t & 63;
    const int n = blockIdx.x * 4 + (t >> 6);
    const float* xr = x + (size_t)n * DDIM;
    double acc[NEXP];
#pragma unroll
    for (int e = 0; e < NEXP; ++e) acc[e] = 0.0;
#pragma unroll
    for (int j = 0; j < 4; ++j) {
        const int d = j * 256 + lane * 4;
        float4 v = *(const float4*)(xr + d);
        unsigned long long pk =
            (unsigned long long)(f2b(v.x) | ((unsigned int)f2b(v.y) << 16)) |
            ((unsigned long long)(f2b(v.z) | ((unsigned int)f2b(v.w) << 16)) << 32);
        *(unsigned long long*)(xb + (size_t)n * DDIM + d) = pk;
#pragma unroll
        for (int e = 0; e < NEXP; ++e) {
            const float* w = wr + e * DDIM + d;
            acc[e] += (double)v.x * (double)w[0];
            acc[e] += (double)v.y * (double)w[1];
            acc[e] += (double)v.z * (double)w[2];
            acc[e] += (double)v.w * (double)w[3];
        }
    }
#pragma unroll
    for (int e = 0; e < NEXP; ++e)
#pragma unroll
        for (int off = 32; off > 0; off >>= 1)
            acc[e] += __shfl_down(acc[e], off);
    if (lane == 0) {
        double best = acc[0] + (double)br[0];
        int bi = 0;
#pragma unroll
        for (int e = 1; e < NEXP; ++e) {
            double v = acc[e] + (double)br[e];
            if (v > best) { best = v; bi = e; }   // strict > == first-max tiebreak
        }
        eid[n] = bi;
    }
}

// K2: histogram — per-block LDS counts, then <=8 padded global atomics/block.
// counts are padded to 64B/entry (counts[e*16]) so the 8 experts hit 8 lines.
__global__ __launch_bounds__(256)
void k_hist(const int* __restrict__ eid, int* __restrict__ counts)
{
    __shared__ int h[NEXP];
    const int t = threadIdx.x;
    if (t < NEXP) h[t] = 0;
    __syncthreads();
    atomicAdd(&h[eid[blockIdx.x * 256 + t]], 1);
    __syncthreads();
    if (t < NEXP && h[t]) atomicAdd(&counts[t * 16], h[t]);
}

// K3: tile table from counts (single thread; E=8, <=136 tiles)
__global__ void k_scan(const int* __restrict__ counts, int* __restrict__ texp,
                       int* __restrict__ pbase)
{
    if (threadIdx.x == 0) {
        int tt = 0;
        for (int e = 0; e < NEXP; ++e) {
            pbase[e] = tt * BM;
            const int nt = (counts[e * 16] + BM - 1) / BM;
            for (int i = 0; i < nt; ++i) texp[tt++] = e;
        }
        for (; tt < MAXMT; ++tt) texp[tt] = -1;
    }
}

// K4: scatter — LDS rank within block + one padded global atomic per
// (block, expert) for the block base. 512 global atomics total, 8 lines.
__global__ __launch_bounds__(256)
void k_scatter(const int* __restrict__ eid, const int* __restrict__ pbase,
               int* __restrict__ cursors, int* __restrict__ perm)
{
    __shared__ int h[NEXP];
    __shared__ int base[NEXP];
    const int t = threadIdx.x;
    if (t < NEXP) h[t] = 0;
    __syncthreads();
    const int n = blockIdx.x * 256 + t;
    const int e = eid[n];
    const int rank = atomicAdd(&h[e], 1);       // LDS atomic: local rank
    __syncthreads();
    if (t < NEXP) base[t] = h[t] ? atomicAdd(&cursors[t * 16], h[t]) : 0;
    __syncthreads();
    perm[pbase[e] + base[e] + rank] = n;
}

// K5a: W_comb[e] = bf16(Ws + We[e]); 8 elems/thread, float4 in, uint4 out
__global__ __launch_bounds__(256)
void k_combine_w(const float* __restrict__ Ws, const float* __restrict__ We,
                 unsigned short* __restrict__ wc)
{
    const size_t i = ((size_t)blockIdx.x * 256 + threadIdx.x) * 8;
    const size_t hd = i & (size_t)(HDIM * DDIM - 1);   // H*D = 2^22
    float4 a0 = *(const float4*)(We + i);
    float4 a1 = *(const float4*)(We + i + 4);
    float4 b0 = *(const float4*)(Ws + hd);
    float4 b1 = *(const float4*)(Ws + hd + 4);
    uint4 o;
    o.x = f2b(a0.x + b0.x) | ((unsigned)f2b(a0.y + b0.y) << 16);
    o.y = f2b(a0.z + b0.z) | ((unsigned)f2b(a0.w + b0.w) << 16);
    o.z = f2b(a1.x + b1.x) | ((unsigned)f2b(a1.y + b1.y) << 16);
    o.w = f2b(a1.z + b1.z) | ((unsigned)f2b(a1.w + b1.w) << 16);
    *(uint4*)(wc + i) = o;
}

// K5b: b_comb[e] = bs + be[e]
__global__ __launch_bounds__(256)
void k_combine_b(const float* __restrict__ bs, const float* __restrict__ be,
                 float* __restrict__ bc)
{
    const int i = blockIdx.x * 256 + threadIdx.x;
    bc[i] = bs[i & (HDIM - 1)] + be[i];
}

// K6: gathered GEMM out[tok,h] = xb[tok,:] @ W_comb[e].T + b_comb[e]
// 128x128 tile, BK=64, 4 waves (2x2), 16x16x32 bf16 MFMA, global_load_lds staging.
__global__ __launch_bounds__(256, 2)
void k_gemm(const unsigned short* __restrict__ X, const unsigned short* __restrict__ W,
            const float* __restrict__ bc, const int* __restrict__ perm,
            const int* __restrict__ texp, float* __restrict__ out)
{
    __shared__ unsigned short lA[BM * 64];   // [128 rows][64 k] bf16
    __shared__ unsigned short lB[BM * 64];   // [128 h][64 k]
    const int tm = blockIdx.y;
    const int e = texp[tm];
    if (e < 0) return;                        // block-uniform: safe
    const int tn = blockIdx.x;
    const int t = threadIdx.x;
    const int lane = t & 63;
    const int wid = t >> 6;
    const int wm = wid >> 1, wn = wid & 1;

    // staging geometry: block round r covers rows [32r,32r+32), lane-linear LDS
    const int rowC = t >> 3;                  // 0..31
    const int colE = (t & 7) << 3;            // k elem 0..56

    int tokA[4];
#pragma unroll
    for (int r = 0; r < 4; ++r) {
        const int tok = perm[tm * BM + r * 32 + rowC];
        tokA[r] = tok < 0 ? 0 : tok;          // dummy rows read token 0, never stored
    }
    const unsigned short* Wb = W + ((size_t)e * HDIM + (size_t)tn * 128) * DDIM;

    f32x4 acc[4][4];
#pragma unroll
    for (int m = 0; m < 4; ++m)
#pragma unroll
        for (int n = 0; n < 4; ++n) acc[m][n] = (f32x4){0.f, 0.f, 0.f, 0.f};

    unsigned short* ldsA = &lA[t * 8];        // lane-linear: byte t*16 within round chunk
    unsigned short* ldsB = &lB[t * 8];

    for (int kt = 0; kt < DDIM / 64; ++kt) {
        const int kb = kt * 64;
        __syncthreads();                      // prev compute done before overwrite
#pragma unroll
        for (int r = 0; r < 4; ++r) {
            const unsigned short* src = X + (size_t)tokA[r] * DDIM + kb + colE;
            __builtin_amdgcn_global_load_lds(
                (const __attribute__((address_space(1))) void*)src,
                (__attribute__((address_space(3))) void*)(ldsA + r * 2048), 16, 0, 0);
        }
#pragma unroll
        for (int r = 0; r < 4; ++r) {
            const unsigned short* src = Wb + (size_t)(r * 32 + rowC) * DDIM + kb + colE;
            __builtin_amdgcn_global_load_lds(
                (const __attribute__((address_space(1))) void*)src,
                (__attribute__((address_space(3))) void*)(ldsB + r * 2048), 16, 0, 0);
        }
        __syncthreads();                      // compiler drains vmcnt before s_barrier
#pragma unroll
        for (int ks = 0; ks < 2; ++ks) {
            const int ko = ks * 32 + (lane >> 4) * 8;
            short8 fa[4], fb[4];
#pragma unroll
            for (int m = 0; m < 4; ++m)
                fa[m] = *(const short8*)&lA[(wm * 64 + m * 16 + (lane & 15)) * 64 + ko];
#pragma unroll
            for (int n = 0; n < 4; ++n)
                fb[n] = *(const short8*)&lB[(wn * 64 + n * 16 + (lane & 15)) * 64 + ko];
#pragma unroll
            for (int m = 0; m < 4; ++m)
#pragma unroll
                for (int n = 0; n < 4; ++n)
                    acc[m][n] = __builtin_amdgcn_mfma_f32_16x16x32_bf16(
                        fa[m], fb[n], acc[m][n], 0, 0, 0);
        }
    }

    // epilogue: C/D layout col=lane&15, row=(lane>>4)*4+reg; fused bias, scatter by token
    const int colBase = tn * 128 + wn * 64 + (lane & 15);
    float bias[4];
#pragma unroll
    for (int n = 0; n < 4; ++n) bias[n] = bc[e * HDIM + colBase + n * 16];
    const int rsub = (lane >> 4) * 4;
#pragma unroll
    for (int m = 0; m < 4; ++m) {
        const int rbase = tm * BM + wm * 64 + m * 16 + rsub;
        int tk[4];
#pragma unroll
        for (int j = 0; j < 4; ++j) tk[j] = perm[rbase + j];
#pragma unroll
        for (int n = 0; n < 4; ++n) {
            const int col = colBase + n * 16;
#pragma unroll
            for (int j = 0; j < 4; ++j)
                if (tk[j] >= 0) out[(size_t)tk[j] * HDIM + col] = acc[m][n][j] + bias[n];
        }
    }
}

extern "C" void kernel_launch(void* const* d_in, const int* in_sizes, int n_in,
                              void* d_out, int out_size, void* d_ws, size_t ws_size,
                              hipStream_t stream)
{
    const float* x  = (const float*)d_in[0];
    const float* Ws = (const float*)d_in[1];
    const float* bs = (const float*)d_in[2];
    const float* We = (const float*)d_in[3];
    const float* be = (const float*)d_in[4];
    const float* Wr = (const float*)d_in[5];
    const float* br = (const float*)d_in[6];
    float* out = (float*)d_out;
    char* ws = (char*)d_ws;

    // workspace layout (~100.93 MB)
    unsigned short* xb  = (unsigned short*)(ws + 0);          // 33,554,432 B
    unsigned short* wc  = (unsigned short*)(ws + 33554432);   // 67,108,864 B
    float*          bc  = (float*)(ws + 100663296);           //    131,072 B
    int*            eid = (int*)(ws + 100794368);             //     65,536 B
    int*            perm= (int*)(ws + 100859904);             //     69,632 B
    int*            cnt = (int*)(ws + 100929536);             // 512 B (padded: cnt[e*16])
    int*            cur = (int*)(ws + 100930048);             // 512 B (padded: cur[e*16])
    int*            pb  = (int*)(ws + 100930560);             // 32 B
    int*            texp= (int*)(ws + 100930592);             // 544 B

    hipMemsetAsync(perm, 0xFF, MAXMT * BM * sizeof(int), stream);
    hipMemsetAsync(cnt, 0, 1024, stream);   // cnt + cur (contiguous)

    k_router_cast<<<N_TOK / 4, 256, 0, stream>>>(x, Wr, br, xb, eid);
    k_combine_w<<<(NEXP * (size_t)HDIM * DDIM / 8) / 256, 256, 0, stream>>>(Ws, We, wc);
    k_combine_b<<<NEXP * HDIM / 256, 256, 0, stream>>>(bs, be, bc);
    k_hist<<<N_TOK / 256, 256, 0, stream>>>(eid, cnt);
    k_scan<<<1, 64, 0, stream>>>(cnt, texp, pb);
    k_scatter<<<N_TOK / 256, 256, 0, stream>>>(eid, pb, cur, perm);
    k_gemm<<<dim3(HDIM / 128, MAXMT), 256, 0, stream>>>(xb, wc, bc, perm, texp, out);
}